// Round 7
// baseline (383.237 us; speedup 1.0000x reference)
//
#include <hip/hip_runtime.h>
#include <hip/hip_bf16.h>

// CoarseGraining: y[i,b] = heg[b] * sum_j exp(-beta[j,b] * d2(i,j)) * wrho[j]
// N = M = 8192, NB = 16, WIDTH = 32. Inputs float32, output float32.
// R10 wave-per-i: 183us. R11 2 i's/wave: 155us. R12 j-split x2: 181us (VGPR).
// R13 float2-packed math: 133us cg_pairs (VALUBusy 79%, HBM 0.3%).
// R14 FAILED: fast-math folded magic-number range reduction.
// R15 deg-5 poly + loop restructure: 190us -- confounded (lambda/prefetch
//   restructure broke scheduling; op-count says poly ~ hw).
// R16 Morton+skip guards: 258us (guards never fire).
// R17/R18 launch_bounds(_,8): VGPR cap = 256/arg = 32 -> spill -> 161-163us.
// R19 j-split x2, (256,4), VGPR 60, no spill, 8192 waves: 135.5us = R13.
//   TLP conclusively NOT the lever. Model: exp all-in ~16.2cy on the trans
//   pipe (VALUBusy counts ~13 -> 79%); 623cy/iter = 32*16.2 + 38*2 + ~30.
//   We sit at ~100% of the hw-exp execution wall.
// R20: break the wall -- R13's EXACT loop (unroll 2, straight-line body,
//   1024 blocks x 256, 2 i/wave), ALL 16 exp-pairs -> deg-4 packed-FMA exp2:
//   clamp p>=-126 (pk_max), trunc/cvt range reduction (fold-opaque, unlike
//   R14), scale = (ni+127)<<23 int-side, Taylor-at-center coeffs err ~5e-5.
//   ~28-32cy/pair full-rate vs hw 36cy. launch_bounds(256,2): VGPR cap 128,
//   no 64-cap spill risk; 4 waves/SIMD proven sufficient (R19).
// Prediction: <=120us poly wins; 125-140 wash -> declare roofline; >=145
//   revert. VALUBusy 88-95%, VGPR 70-95, WRITE ~0.5MB, absmax <= ~1e-3.

#define N_PTS 8192
#define M_PTS 8192
#define NBASIS 16
#define WIDTH 32

typedef float v2f __attribute__((ext_vector_type(2)));

__device__ __forceinline__ float exp2_hw(float x) { return __builtin_amdgcn_exp2f(x); }
__device__ __forceinline__ float log2_hw(float x) { return __builtin_amdgcn_logf(x); }

__device__ __forceinline__ float fast_tanh(float z) {
    float a = fabsf(z);
    float t = __expf(-2.0f * a);
    float r = (1.0f - t) / (1.0f + t);
    return copysignf(r, z);
}

__device__ __forceinline__ float log_cosh_f(float x) {
    float a = fabsf(x);
    return a + __logf(1.0f + __expf(-2.0f * a)) - 0.6931471805599453f;
}

// Packed exp2 for p <= 0, all full-rate ops, fold-immune range reduction.
// pc = max(p, -126); nf = trunc(pc); r = pc - nf in (-1, 0]; ni = (int)pc
// (cvt_i32 truncates = nf); scale s = bit_cast((ni+127)<<23); deg-4 poly in
// r on [-1,0] (Taylor at r=-0.5 expanded; max rel err ~5.6e-5 at endpoints).
// Verified: q(0)=0.99996903, q(-0.5)=0.70710677, q(-1)=0.50002813.
__device__ __forceinline__ v2f exp2_pair_poly(v2f p) {
    v2f pc = { fmaxf(p.x, -126.0f), fmaxf(p.y, -126.0f) };
    v2f nf = { truncf(pc.x), truncf(pc.y) };
    v2f r  = pc - nf;                       // (-1, 0], exact
    int nix = (int)pc.x;                    // v_cvt_i32_f32 truncates == nf
    int niy = (int)pc.y;
    v2f q = r * 0.00680097f + 0.05284924f;
    q = q * r + 0.23893938f;
    q = q * r + 0.69283201f;
    q = q * r + 0.99996903f;
    v2f s = { __builtin_bit_cast(float, ((unsigned)(nix + 127)) << 23),
              __builtin_bit_cast(float, ((unsigned)(niy + 127)) << 23) };
    return q * s;
}

// ---------------- Stage 1: per-source-point quantities ----------------
// cw[j]        = (cx, cy, cz, wrho)
// bnq[q*N + j] = float4{ bn[j][4q..4q+3] }, bn = -log2(e)*beta (q-plane layout)
// hegf[0..15]  = log_cosh(embed(0))^1.5
__global__ __launch_bounds__(64)
void cg_prep(const float* __restrict__ rho,
             const float* __restrict__ gamma,
             const float* __restrict__ coords,
             const float* __restrict__ weights,
             const float* __restrict__ w1,
             const float* __restrict__ b1,
             const float* __restrict__ w2,
             const float* __restrict__ b2,
             float4* __restrict__ cw,
             float4* __restrict__ bnq,
             float* __restrict__ hegf)
{
    const float PI_F = 3.14159265358979323846f;
    const float LOG2E = 1.4426950408889634f;

    __shared__ float s_w1[WIDTH], s_b1[WIDTH], s_w2[WIDTH * NBASIS], s_b2[NBASIS];
    int t = threadIdx.x;
    if (t < WIDTH) { s_w1[t] = w1[t]; s_b1[t] = b1[t]; }
    if (t < NBASIS) s_b2[t] = b2[t];
    #pragma unroll
    for (int k = 0; k < 8; ++k) s_w2[t + 64 * k] = w2[t + 64 * k];
    __syncthreads();

    int j = blockIdx.x * 64 + t;
    {
        float r = rho[j];
        float g = gamma[j];
        const float c83 = 38.28312007948569f;              // 4*(3*pi^2)^(2/3)
        float r83 = exp2_hw(2.6666666667f * log2_hw(r));   // r^(8/3)
        float s2 = g / (c83 * r83);
        float x = __logf(s2 + 1e-4f);

        float emb[NBASIS];
        #pragma unroll
        for (int b = 0; b < NBASIS; ++b) emb[b] = s_b2[b];
        #pragma unroll 4
        for (int w = 0; w < WIDTH; ++w) {
            float h = fast_tanh(fmaf(x, s_w1[w], s_b1[w]));
            #pragma unroll
            for (int b = 0; b < NBASIS; ++b)
                emb[b] = fmaf(h, s_w2[w * NBASIS + b], emb[b]);
        }
        float pref = PI_F * exp2_hw(0.6666666667f * log2_hw(0.5f * r));
        float scale = -LOG2E * pref;
        #pragma unroll
        for (int q = 0; q < 4; ++q) {
            bnq[q * N_PTS + j] = make_float4(scale * log_cosh_f(emb[4 * q + 0]),
                                             scale * log_cosh_f(emb[4 * q + 1]),
                                             scale * log_cosh_f(emb[4 * q + 2]),
                                             scale * log_cosh_f(emb[4 * q + 3]));
        }

        cw[j] = make_float4(coords[j * 3 + 0],
                            coords[j * 3 + 1],
                            coords[j * 3 + 2],
                            weights[j] * r);
    }

    if (blockIdx.x == 0 && t == 0) {
        float emb0[NBASIS];
        #pragma unroll
        for (int b = 0; b < NBASIS; ++b) emb0[b] = s_b2[b];
        for (int w = 0; w < WIDTH; ++w) {
            float h = fast_tanh(s_b1[w]);   // x = 0
            #pragma unroll
            for (int b = 0; b < NBASIS; ++b)
                emb0[b] = fmaf(h, s_w2[w * NBASIS + b], emb0[b]);
        }
        #pragma unroll
        for (int b = 0; b < NBASIS; ++b) {
            float lc = fmaxf(log_cosh_f(emb0[b]), 0.0f);
            hegf[b] = lc * sqrtf(lc);       // lc^1.5
        }
    }
}

// ---------------- Stage 2: all-pairs, 2 i's/wave, poly exp ----------------
// R13 structure exactly (1024 blocks x 256 = 4096 waves, unroll 2,
// unconditional loads), exp pairs via exp2_pair_poly (full-rate only).
__global__ __launch_bounds__(256, 2)
void cg_pairs(const float* __restrict__ oc,
              const float4* __restrict__ cw,
              const float4* __restrict__ bnq,
              const float* __restrict__ hegf,
              float* __restrict__ out)
{
    int wave = (blockIdx.x << 2) | (threadIdx.x >> 6);
    int lane = threadIdx.x & 63;
    int i0 = wave << 1;
    int i1 = i0 | 1;

    v2f oxv = { oc[i0 * 3 + 0], oc[i1 * 3 + 0] };
    v2f oyv = { oc[i0 * 3 + 1], oc[i1 * 3 + 1] };
    v2f ozv = { oc[i0 * 3 + 2], oc[i1 * 3 + 2] };

    v2f acc[NBASIS];
    #pragma unroll
    for (int b = 0; b < NBASIS; ++b) acc[b] = (v2f)0.0f;

    #pragma unroll 2
    for (int k = 0; k < N_PTS / 64; ++k) {
        int j = (k << 6) | lane;                 // lane-consecutive: coalesced
        float4 c = cw[j];
        v2f dx = oxv - c.x;                      // pk_add (scalar broadcast)
        v2f dy = oyv - c.y;
        v2f dz = ozv - c.z;
        v2f d2 = dx * dx + dy * dy + dz * dz;    // pk_mul + 2x pk_fma
        #pragma unroll
        for (int q = 0; q < 4; ++q) {
            float4 b4 = bnq[q * N_PTS + j];      // coalesced dwordx4
            v2f p0 = b4.x * d2;                  // pk_mul
            v2f p1 = b4.y * d2;
            v2f p2 = b4.z * d2;
            v2f p3 = b4.w * d2;
            v2f e0 = exp2_pair_poly(p0);
            v2f e1 = exp2_pair_poly(p1);
            v2f e2 = exp2_pair_poly(p2);
            v2f e3 = exp2_pair_poly(p3);
            acc[q * 4 + 0] += e0 * c.w;          // pk_fma
            acc[q * 4 + 1] += e1 * c.w;
            acc[q * 4 + 2] += e2 * c.w;
            acc[q * 4 + 3] += e3 * c.w;
        }
    }

    // 6-step butterfly over 64 lanes, 16 v2f values
    #pragma unroll
    for (int m = 1; m < 64; m <<= 1) {
        #pragma unroll
        for (int b = 0; b < NBASIS; ++b) {
            v2f other = { __shfl_xor(acc[b].x, m, 64),
                          __shfl_xor(acc[b].y, m, 64) };
            acc[b] += other;
        }
    }

    if (lane == 0) {
        #pragma unroll
        for (int b = 0; b < NBASIS; ++b) {
            float h = hegf[b];                   // wave-uniform s_load
            out[i0 * NBASIS + b] = acc[b].x * h;
            out[i1 * NBASIS + b] = acc[b].y * h;
        }
    }
}

extern "C" void kernel_launch(void* const* d_in, const int* in_sizes, int n_in,
                              void* d_out, int out_size, void* d_ws, size_t ws_size,
                              hipStream_t stream) {
    const float* rho        = (const float*)d_in[0];
    const float* gamma      = (const float*)d_in[1];
    const float* coords     = (const float*)d_in[2];
    const float* weights    = (const float*)d_in[3];
    const float* out_coords = (const float*)d_in[4];
    const float* w1         = (const float*)d_in[5];
    const float* b1         = (const float*)d_in[6];
    const float* w2         = (const float*)d_in[7];
    const float* b2         = (const float*)d_in[8];

    char* ws = (char*)d_ws;
    // ws layout (640 KiB + 64 B):
    //   cw   : N * float4              = 128 KiB  @ 0
    //   bnq  : 4 planes * N * float4   = 512 KiB  @ 128K
    //   hegf : 16 * float                          @ 640K
    float4* cw   = (float4*)(ws);
    float4* bnq  = (float4*)(ws + (128 << 10));
    float*  hegf = (float*) (ws + (640 << 10));

    cg_prep<<<N_PTS / 64, 64, 0, stream>>>(rho, gamma, coords, weights,
                                           w1, b1, w2, b2,
                                           cw, bnq, hegf);

    cg_pairs<<<M_PTS / 8, 256, 0, stream>>>(out_coords, cw, bnq, hegf,
                                            (float*)d_out);
}